// Round 1
// baseline (291.142 us; speedup 1.0000x reference)
//
#include <hip/hip_runtime.h>
#include <hip/hip_cooperative_groups.h>

namespace cg = cooperative_groups;

#define B 16384
#define D 1024
#define CL_ALPHA 0.5f
#define MAXM 16   // max samples per class; P(Poisson(1) > 16) ~ 1e-14 per class
#define INV_BD (1.0f / ((float)B * (float)D))

// Per-class work, one WAVE per class: lane owns 4 float4 chunks (chunk c ->
// float4 index c*64+lane, i.e. 4 coalesced 1KB segments per row).
// Returns sum over class members i of || y_pred[i] + corr_j ||^2 (0 if empty).
__device__ __forceinline__ float class_wave_acc(
    int j, int lane,
    const int* __restrict__ y_true, const float* __restrict__ y_pred,
    const float* __restrict__ centers, const int* __restrict__ counts,
    const int* __restrict__ list)
{
    const int m = counts[j];
    if (m == 0) return 0.0f;                  // ~37.9% of classes
    const int mm = (m < MAXM) ? m : MAXM;

    // issue member-list load early; broadcast later via shfl (no LDS, no barrier)
    int mem = (lane < mm) ? list[j * MAXM + lane] : 0;
    const int kk = y_true[j];

    const float4* cjp = (const float4*)(centers + j * D);
    const float4* yjp = (const float4*)(y_pred  + j * D);
    const float4* ckp = (const float4*)(centers + kk * D);

    float4 cj[4], yj[4], ck[4];
#pragma unroll
    for (int c = 0; c < 4; ++c) {             // 12 independent 16B loads in flight
        cj[c] = cjp[c * 64 + lane];
        yj[c] = yjp[c * 64 + lane];
        ck[c] = ckp[c * 64 + lane];
    }
    const float inv = CL_ALPHA / ((float)counts[kk] + 1.0f);

    // corr = inv*(centers[kk] - y_pred[j]) - centers[j]  (same formula/rounding
    // as the previously-verified kernel)
    float4 corr[4];
#pragma unroll
    for (int c = 0; c < 4; ++c) {
        corr[c].x = inv * (ck[c].x - yj[c].x) - cj[c].x;
        corr[c].y = inv * (ck[c].y - yj[c].y) - cj[c].y;
        corr[c].z = inv * (ck[c].z - yj[c].z) - cj[c].z;
        corr[c].w = inv * (ck[c].w - yj[c].w) - cj[c].w;
    }

    float acc = 0.0f;
    for (int s = 0; s < mm; ++s) {
        const int i = __shfl(mem, s, 64);
        const float4* ap = (const float4*)(y_pred + i * D);
#pragma unroll
        for (int c = 0; c < 4; ++c) {
            float4 a = ap[c * 64 + lane];
            float dx = a.x + corr[c].x;
            float dy = a.y + corr[c].y;
            float dz = a.z + corr[c].z;
            float dw = a.w + corr[c].w;
            acc += dx * dx + dy * dy + dz * dz + dw * dw;
        }
    }
    return acc;
}

// Wave reduce -> block reduce -> one atomicAdd per block (pre-scaled).
__device__ __forceinline__ void block_reduce_atomic(float acc, float* out)
{
#pragma unroll
    for (int off = 32; off > 0; off >>= 1)
        acc += __shfl_down(acc, off, 64);

    __shared__ float smem[4];
    const int lane = threadIdx.x & 63;
    const int wid  = threadIdx.x >> 6;
    if (lane == 0) smem[wid] = acc;
    __syncthreads();
    if (threadIdx.x == 0)
        atomicAdd(out, (smem[0] + smem[1] + smem[2] + smem[3]) * INV_BD);
}

// Single fused cooperative kernel: zero -> bincount+lists -> per-class loop.
// All blocks co-resident (grid sized from occupancy query at launch).
__global__ __launch_bounds__(256, 4) void fused_kernel(
    const int* __restrict__ y_true, const float* __restrict__ y_pred,
    const float* __restrict__ centers, int* __restrict__ counts,
    int* __restrict__ list, float* __restrict__ out)
{
    cg::grid_group grid = cg::this_grid();
    const int nth  = gridDim.x * 256;
    const int gtid = blockIdx.x * 256 + threadIdx.x;

    // Phase A: zero counts + out (replaces hipMemsetAsync + finalize's zero)
    for (int i = gtid; i < B; i += nth) counts[i] = 0;
    if (gtid == 0) out[0] = 0.0f;
    grid.sync();

    // Phase B: bincount + per-class member lists
    for (int i = gtid; i < B; i += nth) {
        const int j = y_true[i];
        const int slot = atomicAdd(&counts[j], 1);
        if (slot < MAXM) list[j * MAXM + slot] = i;
    }
    grid.sync();

    // Phase C: persistent waves, one class per wave per step
    const int lane   = threadIdx.x & 63;
    const int gw     = blockIdx.x * 4 + (threadIdx.x >> 6);
    const int nwaves = gridDim.x * 4;
    float acc = 0.0f;
    for (int j = gw; j < B; j += nwaves)
        acc += class_wave_acc(j, lane, y_true, y_pred, centers, counts, list);

    block_reduce_atomic(acc, out);
}

// ---------- non-cooperative fallback path (only used if coop launch fails) ----------
__global__ void build_kernel(const int* __restrict__ y_true, int* __restrict__ counts,
                             int* __restrict__ list, float* __restrict__ out)
{
    const int i = blockIdx.x * blockDim.x + threadIdx.x;
    if (i == 0) out[0] = 0.0f;          // ordered before class_kernel_fb's atomics
    if (i >= B) return;
    const int j = y_true[i];
    const int slot = atomicAdd(&counts[j], 1);
    if (slot < MAXM) list[j * MAXM + slot] = i;
}

__global__ __launch_bounds__(256, 4) void class_kernel_fb(
    const int* __restrict__ y_true, const float* __restrict__ y_pred,
    const float* __restrict__ centers, const int* __restrict__ counts,
    const int* __restrict__ list, float* __restrict__ out)
{
    const int lane = threadIdx.x & 63;
    const int j = blockIdx.x * 4 + (threadIdx.x >> 6);   // one wave per class
    float acc = class_wave_acc(j, lane, y_true, y_pred, centers, counts, list);
    block_reduce_atomic(acc, out);
}

extern "C" void kernel_launch(void* const* d_in, const int* in_sizes, int n_in,
                              void* d_out, int out_size, void* d_ws, size_t ws_size,
                              hipStream_t stream)
{
    const int*   y_true  = (const int*)d_in[0];
    const float* y_pred  = (const float*)d_in[1];
    const float* centers = (const float*)d_in[2];
    float* out = (float*)d_out;

    // Workspace: counts (64KB) | list (1MB)
    int* counts = (int*)d_ws;
    int* list   = counts + B;

    static int nb = -1;
    if (nb < 0) {
        int dev = 0;
        (void)hipGetDevice(&dev);
        hipDeviceProp_t prop;
        int cus = 256;
        if (hipGetDeviceProperties(&prop, dev) == hipSuccess && prop.multiProcessorCount > 0)
            cus = prop.multiProcessorCount;
        int perCU = 0;
        if (hipOccupancyMaxActiveBlocksPerMultiprocessor(&perCU, fused_kernel, 256, 0) != hipSuccess
            || perCU < 1)
            perCU = 1;
        long total = (long)perCU * (long)cus;
        if (total > 4096) total = 4096;   // >= 1 class per wave step, no waste
        if (total < 64)   total = 64;
        nb = (int)total;
    }

    const int*   yt = y_true;
    const float* yp = y_pred;
    const float* ce = centers;
    int* cn = counts;
    int* ls = list;
    float* ou = out;
    void* args[] = { &yt, &yp, &ce, &cn, &ls, &ou };

    hipError_t err = hipLaunchCooperativeKernel((const void*)fused_kernel,
                                                dim3(nb), dim3(256), args, 0, stream);
    if (err != hipSuccess) {
        (void)hipGetLastError();   // clear sticky error, use classic 3-node path
        hipMemsetAsync(counts, 0, B * sizeof(int), stream);
        build_kernel<<<B / 256, 256, 0, stream>>>(y_true, counts, list, out);
        class_kernel_fb<<<B / 4, 256, 0, stream>>>(y_true, y_pred, centers, counts, list, out);
    }
}

// Round 2
// 179.678 us; speedup vs baseline: 1.6204x; 1.6204x over previous
//
#include <hip/hip_runtime.h>

#define B 16384
#define D 1024
#define CL_ALPHA 0.5f
#define MAXM 16   // max samples per class; P(Poisson(1) > 16) ~ 1e-14 per class
#define CPB 8     // classes per block in class_kernel
#define INV_BD (1.0f / ((float)B * (float)D))

// ---------------------------------------------------------------------------
// Pass 1 (single block): fused {memset + bincount + member lists + out=0}.
// 16384-bin histogram lives entirely in LDS (64 KB of the 160 KB/CU).
// Replaces the old hipMemsetAsync + 64-block build + finalize-zero: one node.
// ---------------------------------------------------------------------------
__global__ __launch_bounds__(1024) void build_kernel(const int* __restrict__ y_true,
                                                     int* __restrict__ counts,
                                                     int* __restrict__ list,
                                                     float* __restrict__ out)
{
    __shared__ int h[B];
    const int t = threadIdx.x;
#pragma unroll
    for (int w = 0; w < B / 1024; ++w) h[t + 1024 * w] = 0;
    if (t == 0) out[0] = 0.0f;
    __syncthreads();

    const int4* y4 = (const int4*)y_true;   // B is a multiple of 4096
#pragma unroll
    for (int w = 0; w < B / 4096; ++w) {
        const int4 v = y4[t + 1024 * w];
        const int i0 = 4 * (t + 1024 * w);
        int s;
        s = atomicAdd(&h[v.x], 1); if (s < MAXM) list[v.x * MAXM + s] = i0;
        s = atomicAdd(&h[v.y], 1); if (s < MAXM) list[v.y * MAXM + s] = i0 + 1;
        s = atomicAdd(&h[v.z], 1); if (s < MAXM) list[v.z * MAXM + s] = i0 + 2;
        s = atomicAdd(&h[v.w], 1); if (s < MAXM) list[v.w * MAXM + s] = i0 + 3;
    }
    __syncthreads();
#pragma unroll
    for (int w = 0; w < B / 1024; ++w) counts[t + 1024 * w] = h[t + 1024 * w];
}

// ---------------------------------------------------------------------------
// Pass 2: 2048 blocks x 256 threads, CPB=8 classes per block.
//  - metadata chain (counts[j], y_true[j], counts[kk], list) done ONCE per 8
//    classes in 2 parallel latency rounds (was ~3 serial rounds PER class)
//  - nonempty classes compacted into LDS -> branch-free pipelined main loop
//  - software pipeline: issue next class's 3 rows + current class's member
//    rows BEFORE consuming current rows (counted vmcnt keeps them in flight)
//  - per-block atomicAdd into out[0] replaces the finalize kernel
// ---------------------------------------------------------------------------
__device__ __forceinline__ float4 ldrow(const float* __restrict__ p, int row, int t)
{
    return ((const float4*)(p + (size_t)row * D))[t];
}

__global__ __launch_bounds__(256) void class_kernel(const int* __restrict__ y_true,
                                                    const float* __restrict__ y_pred,
                                                    const float* __restrict__ centers,
                                                    const int* __restrict__ counts,
                                                    const int* __restrict__ list,
                                                    float* __restrict__ out)
{
    const int t  = threadIdx.x;
    const int j0 = blockIdx.x * CPB;

    __shared__ int   sm_m[CPB];
    __shared__ int   sm_kk[CPB];
    __shared__ float sm_inv[CPB];
    __shared__ int   sm_mem[CPB][MAXM];
    __shared__ int   sm_cls[CPB];
    __shared__ int   sm_n;

    if (t == 0) sm_n = 0;
    __syncthreads();

    // ---- metadata: one parallel round + one dependent round (threads 144+) ----
    if (t < CPB * MAXM)                       // 128 ints, contiguous 512B
        sm_mem[t >> 4][t & 15] = list[j0 * MAXM + t];
    if (t >= 128 && t < 128 + CPB) {
        const int c = t - 128;
        const int m = counts[j0 + c];
        sm_m[c] = m;
        if (m > 0) { const int p = atomicAdd(&sm_n, 1); sm_cls[p] = c; }
    }
    if (t >= 144 && t < 144 + CPB) {
        const int c  = t - 144;
        const int kk = y_true[j0 + c];
        sm_kk[c]  = kk;
        sm_inv[c] = CL_ALPHA / ((float)counts[kk] + 1.0f);   // dependent load
    }
    __syncthreads();

    const int nem = sm_n;
    float acc = 0.0f;

    if (nem > 0) {
        int    c0  = sm_cls[0];
        float4 cj0 = ldrow(centers, j0 + c0, t);
        float4 yj0 = ldrow(y_pred,  j0 + c0, t);
        float4 ck0 = ldrow(centers, sm_kk[c0], t);

        for (int p = 0; p < nem; ++p) {
            // ---- prefetch next class's 3 rows (issued before any wait) ----
            int    c1;
            float4 cj1, yj1, ck1;
            if (p + 1 < nem) {
                c1  = sm_cls[p + 1];
                cj1 = ldrow(centers, j0 + c1, t);
                yj1 = ldrow(y_pred,  j0 + c1, t);
                ck1 = ldrow(centers, sm_kk[c1], t);
            } else {
                c1 = c0; cj1 = cj0; yj1 = yj0; ck1 = ck0;
            }

            const int mraw = sm_m[c0];
            const int mm   = (mraw < MAXM) ? mraw : MAXM;

            // ---- member rows: loads are independent of corr; issue now ----
            float4 a0, a1, a2, a3;
            a0 = ldrow(y_pred, sm_mem[c0][0], t);               // mm >= 1
            if (mm > 1) a1 = ldrow(y_pred, sm_mem[c0][1], t);   // wave-uniform
            if (mm > 2) a2 = ldrow(y_pred, sm_mem[c0][2], t);
            if (mm > 3) a3 = ldrow(y_pred, sm_mem[c0][3], t);

            // ---- corr: first consumption of cj0/yj0/ck0 (counted vmcnt;
            //      next-class rows + member rows stay in flight) ----
            const float inv = sm_inv[c0];
            float4 corr;
            corr.x = inv * (ck0.x - yj0.x) - cj0.x;
            corr.y = inv * (ck0.y - yj0.y) - cj0.y;
            corr.z = inv * (ck0.z - yj0.z) - cj0.z;
            corr.w = inv * (ck0.w - yj0.w) - cj0.w;

            float dx, dy, dz, dw;
            dx = a0.x + corr.x; dy = a0.y + corr.y; dz = a0.z + corr.z; dw = a0.w + corr.w;
            acc += dx * dx + dy * dy + dz * dz + dw * dw;
            if (mm > 1) {
                dx = a1.x + corr.x; dy = a1.y + corr.y; dz = a1.z + corr.z; dw = a1.w + corr.w;
                acc += dx * dx + dy * dy + dz * dz + dw * dw;
            }
            if (mm > 2) {
                dx = a2.x + corr.x; dy = a2.y + corr.y; dz = a2.z + corr.z; dw = a2.w + corr.w;
                acc += dx * dx + dy * dy + dz * dz + dw * dw;
            }
            if (mm > 3) {
                dx = a3.x + corr.x; dy = a3.y + corr.y; dz = a3.z + corr.z; dw = a3.w + corr.w;
                acc += dx * dx + dy * dy + dz * dz + dw * dw;
            }
            for (int s = 4; s < mm; ++s) {      // P(m>4) ~ 0.4%, rare tail
                const float4 a = ldrow(y_pred, sm_mem[c0][s], t);
                dx = a.x + corr.x; dy = a.y + corr.y; dz = a.z + corr.z; dw = a.w + corr.w;
                acc += dx * dx + dy * dy + dz * dz + dw * dw;
            }

            c0 = c1; cj0 = cj1; yj0 = yj1; ck0 = ck1;   // rotate pipeline regs
        }
    }

    // ---- block reduce -> one atomicAdd (replaces finalize kernel) ----
#pragma unroll
    for (int off = 32; off > 0; off >>= 1)
        acc += __shfl_down(acc, off, 64);

    __shared__ float smem[4];
    const int lane = t & 63;
    const int wid  = t >> 6;
    if (lane == 0) smem[wid] = acc;
    __syncthreads();
    if (t == 0) {
        const float s = smem[0] + smem[1] + smem[2] + smem[3];
        if (s != 0.0f) atomicAdd(out, s * INV_BD);
    }
}

extern "C" void kernel_launch(void* const* d_in, const int* in_sizes, int n_in,
                              void* d_out, int out_size, void* d_ws, size_t ws_size,
                              hipStream_t stream)
{
    const int*   y_true  = (const int*)d_in[0];
    const float* y_pred  = (const float*)d_in[1];
    const float* centers = (const float*)d_in[2];
    float* out = (float*)d_out;

    // Workspace: counts (64KB) | list (B*MAXM*4 = 1MB)
    int* counts = (int*)d_ws;
    int* list   = counts + B;

    build_kernel<<<1, 1024, 0, stream>>>(y_true, counts, list, out);
    class_kernel<<<B / CPB, 256, 0, stream>>>(y_true, y_pred, centers, counts, list, out);
}